// Round 1
// baseline (242.645 us; speedup 1.0000x reference)
//
#include <hip/hip_runtime.h>
#include <hip/hip_bf16.h>
#include <stdint.h>

// Problem: B=2, S=2048, F=2048, H=16, DH=128, causal, ROPE_BASE=1e4, fp32 I/O.
#define NB 2
#define NS 2048
#define NFE 2048
#define NH 16
#define NDH 128

typedef __attribute__((ext_vector_type(4))) float f32x4;
typedef __attribute__((ext_vector_type(8))) __bf16 bf16x8;

__device__ __forceinline__ uint16_t f2bf(float f) {
  uint32_t u = __builtin_bit_cast(uint32_t, f);
  return (uint16_t)((u + 0x7fffu + ((u >> 16) & 1u)) >> 16);
}

__device__ __forceinline__ void gload_lds16(const void* g, void* l) {
  __builtin_amdgcn_global_load_lds((const __attribute__((address_space(1))) void*)g,
                                   (__attribute__((address_space(3))) void*)l,
                                   16, 0, 0);
}

#define MFMA16(a, b, c) __builtin_amdgcn_mfma_f32_16x16x32_bf16(a, b, c, 0, 0, 0)

// ---------------- kernel 0a: fp32 -> bf16 convert (in_q) ----------------
__global__ void k_convert(const float* __restrict__ x, uint16_t* __restrict__ y) {
  int i = (blockIdx.x * 256 + threadIdx.x) * 4;
  float4 v = *(const float4*)(x + i);
  ushort4 o;
  o.x = f2bf(v.x); o.y = f2bf(v.y); o.z = f2bf(v.z); o.w = f2bf(v.w);
  *(ushort4*)(y + i) = o;
}

// ---------------- kernel 0b: W transpose+convert: [K][N] f32 -> [N][K] bf16 ---
__global__ void k_wt(const float* __restrict__ Wq, const float* __restrict__ Wk,
                     const float* __restrict__ Wv, uint16_t* __restrict__ Wt) {
  int which = blockIdx.z;
  const float* Wsrc = (which == 0) ? Wq : ((which == 1) ? Wk : Wv);
  int k0 = blockIdx.x * 64, n0 = blockIdx.y * 64;
  __shared__ uint16_t tile[64][65];
  int t = threadIdx.x;
#pragma unroll
  for (int it = 0; it < 4; ++it) {
    int vec = t + it * 256;        // 0..1023
    int r = vec >> 4, c4 = vec & 15;
    float4 v = *(const float4*)&Wsrc[(size_t)(k0 + r) * NFE + n0 + c4 * 4];
    tile[r][c4 * 4 + 0] = f2bf(v.x);
    tile[r][c4 * 4 + 1] = f2bf(v.y);
    tile[r][c4 * 4 + 2] = f2bf(v.z);
    tile[r][c4 * 4 + 3] = f2bf(v.w);
  }
  __syncthreads();
#pragma unroll
  for (int it = 0; it < 4; ++it) {
    int vec = t + it * 256;
    int r = vec >> 4, c4 = vec & 15;   // r = n row, c4*4 = k offset
    ushort4 o;
    o.x = tile[c4 * 4 + 0][r];
    o.y = tile[c4 * 4 + 1][r];
    o.z = tile[c4 * 4 + 2][r];
    o.w = tile[c4 * 4 + 3][r];
    *(ushort4*)&Wt[(size_t)which * NFE * NFE + (size_t)(n0 + r) * NFE + k0 + c4 * 4] = o;
  }
}

// ---------------- kernel 0c: RoPE cos/sin tables [S][64] fp32 ----------------
__global__ void k_rope_tab(float* __restrict__ cosT, float* __restrict__ sinT,
                           const int* __restrict__ offp) {
  int tid = blockIdx.x * 256 + threadIdx.x;   // 0..131071
  int s = tid >> 6, i = tid & 63;
  float off = (float)offp[0];
  float inv = expf(-((float)i / 64.0f) * logf(10000.0f));
  float ang = ((float)s + off) * inv;
  cosT[tid] = cosf(ang);
  sinT[tid] = sinf(ang);
}

// ---------------- kernel 1: QKV GEMM + bias + RoPE -> bf16 q/k/v ----------------
// A: in_q bf16 [4096][2048]; Wt: [3][2048(n)][2048(k)] bf16.
// tile 128(M) x 128(N), BK=64, 4 waves each 32 rows x 128 cols.
// N-tile == one head of one of {q,k,v}; RoPE pairs (d, d+64) are acc[m][nf] / acc[m][nf+4].
__global__ __launch_bounds__(256, 2) void k_gemm_qkv(
    const uint16_t* __restrict__ A, const uint16_t* __restrict__ Wt,
    const float* __restrict__ bq, const float* __restrict__ bk, const float* __restrict__ bv,
    const float* __restrict__ cosT, const float* __restrict__ sinT,
    uint16_t* __restrict__ qws, uint16_t* __restrict__ kws, uint16_t* __restrict__ vws) {
  __shared__ alignas(16) uint16_t Asm[128 * 64];
  __shared__ alignas(16) uint16_t Bsm[128 * 64];
  int mt = blockIdx.x;                 // 0..31
  int nt = blockIdx.y;                 // 0..47
  int which = nt >> 4, h = nt & 15;
  const uint16_t* Bsrc = Wt + (size_t)which * NFE * NFE + (size_t)h * NDH * NFE;
  const uint16_t* Arow = A + (size_t)mt * 128 * NFE;
  int t = threadIdx.x, w = t >> 6, l = t & 63;
  int g = l >> 4, c = l & 15;

  f32x4 acc[2][8];
#pragma unroll
  for (int m = 0; m < 2; ++m)
#pragma unroll
    for (int n = 0; n < 8; ++n) acc[m][n] = (f32x4){0.f, 0.f, 0.f, 0.f};

  for (int kt = 0; kt < NFE / 64; ++kt) {
    int k0 = kt * 64;
    // stage A and B tiles, XOR-swizzled source so swizzled read is conflict-free
#pragma unroll
    for (int cc = 0; cc < 4; ++cc) {
      int flat = cc * 256 + t;         // 0..1023 : row = flat>>3 (128B rows), sub = flat&7
      int row = flat >> 3, sub = flat & 7;
      int scol = ((sub ^ (row & 7)) << 3) + k0;
      gload_lds16(&Arow[(size_t)row * NFE + scol], (char*)Asm + flat * 16);
    }
#pragma unroll
    for (int cc = 0; cc < 4; ++cc) {
      int flat = cc * 256 + t;
      int row = flat >> 3, sub = flat & 7;
      int scol = ((sub ^ (row & 7)) << 3) + k0;
      gload_lds16(&Bsrc[(size_t)row * NFE + scol], (char*)Bsm + flat * 16);
    }
    __syncthreads();
#pragma unroll
    for (int ks = 0; ks < 2; ++ks) {
      bf16x8 af[2];
#pragma unroll
      for (int m = 0; m < 2; ++m) {
        int row = w * 32 + m * 16 + c;
        int kb = ((ks * 32 + g * 8) * 2) ^ ((row & 7) << 4);
        af[m] = *(const bf16x8*)((const char*)Asm + row * 128 + kb);
      }
#pragma unroll
      for (int nf = 0; nf < 8; ++nf) {
        int row = nf * 16 + c;
        int kb = ((ks * 32 + g * 8) * 2) ^ ((row & 7) << 4);
        bf16x8 bfr = *(const bf16x8*)((const char*)Bsm + row * 128 + kb);
        acc[0][nf] = MFMA16(af[0], bfr, acc[0][nf]);
        acc[1][nf] = MFMA16(af[1], bfr, acc[1][nf]);
      }
    }
    __syncthreads();
  }

  // epilogue: bias (+ RoPE for q,k), write bf16 to [bh][s][d]
  const float* bias = (which == 0) ? bq : ((which == 1) ? bk : bv);
  uint16_t* outp = (which == 0) ? qws : ((which == 1) ? kws : vws);
  int mbase = mt * 128 + w * 32;
  if (which < 2) {
#pragma unroll
    for (int m = 0; m < 2; ++m)
#pragma unroll
      for (int nf = 0; nf < 4; ++nf) {
        int i = nf * 16 + c;   // rotary index 0..63
        float b1 = bias[h * NDH + i], b2 = bias[h * NDH + 64 + i];
#pragma unroll
        for (int j = 0; j < 4; ++j) {
          int r = mbase + m * 16 + g * 4 + j;   // global M row
          int bb = r >> 11, s = r & (NS - 1);
          float cs = cosT[(s << 6) + i], sn = sinT[(s << 6) + i];
          float x1 = acc[m][nf][j] + b1;
          float x2 = acc[m][nf + 4][j] + b2;
          uint16_t* op = outp + ((size_t)(bb * NH + h) * NS + s) * NDH;
          op[i] = f2bf(x1 * cs - x2 * sn);
          op[64 + i] = f2bf(x1 * sn + x2 * cs);
        }
      }
  } else {
#pragma unroll
    for (int m = 0; m < 2; ++m)
#pragma unroll
      for (int nf = 0; nf < 8; ++nf) {
        int d = nf * 16 + c;
        float bv_ = bias[h * NDH + d];
#pragma unroll
        for (int j = 0; j < 4; ++j) {
          int r = mbase + m * 16 + g * 4 + j;
          int bb = r >> 11, s = r & (NS - 1);
          outp[((size_t)(bb * NH + h) * NS + s) * NDH + d] = f2bf(acc[m][nf][j] + bv_);
        }
      }
  }
}

// ---------------- kernel 1.5: V transpose [bh][s][d] -> [bh][d][s] ----------------
__global__ void k_vt(const uint16_t* __restrict__ v, uint16_t* __restrict__ vt) {
  int bh = blockIdx.z;
  int s0 = blockIdx.x * 64, d0 = blockIdx.y * 64;
  __shared__ uint16_t tile[64][65];
  int t = threadIdx.x;
#pragma unroll
  for (int it = 0; it < 4; ++it) {
    int vec = t + it * 256;
    int r = vec >> 4, c4 = vec & 15;     // r = s row, c4*4 = d offset
    ushort4 x = *(const ushort4*)&v[((size_t)bh * NS + s0 + r) * NDH + d0 + c4 * 4];
    tile[r][c4 * 4 + 0] = x.x;
    tile[r][c4 * 4 + 1] = x.y;
    tile[r][c4 * 4 + 2] = x.z;
    tile[r][c4 * 4 + 3] = x.w;
  }
  __syncthreads();
#pragma unroll
  for (int it = 0; it < 4; ++it) {
    int vec = t + it * 256;
    int r = vec >> 4, c4 = vec & 15;     // r = d row, c4*4 = s offset
    ushort4 o;
    o.x = tile[c4 * 4 + 0][r];
    o.y = tile[c4 * 4 + 1][r];
    o.z = tile[c4 * 4 + 2][r];
    o.w = tile[c4 * 4 + 3][r];
    *(ushort4*)&vt[((size_t)bh * NDH + d0 + r) * NS + s0 + c4 * 4] = o;
  }
}

// ---------------- kernel 2: causal flash attention ----------------
// q:[32][2048][128], k:[32][2048][128], vT:[32][128][2048] (all bf16), out fp32 [B][S][F].
// Block: 256 thr / 4 waves; Q-tile 128 rows (wave owns 32); K-tile 64.
__global__ __launch_bounds__(256, 2) void k_attn(
    const uint16_t* __restrict__ qws, const uint16_t* __restrict__ kws,
    const uint16_t* __restrict__ vtws, float* __restrict__ out) {
  __shared__ alignas(16) uint16_t Ksm[64 * 128];    // [kv][d]  rows 256B, swizzled
  __shared__ alignas(16) uint16_t Vsm[128 * 64];    // [d][kv]  rows 128B, swizzled
  __shared__ alignas(16) uint16_t Psm[4][32 * 64];  // per-wave [q][kv], swizzled

  int bh = blockIdx.x;                 // 0..31 : b = bh>>4, h = bh&15
  int q0 = blockIdx.y * 128;
  int t = threadIdx.x, w = t >> 6, l = t & 63;
  int g = l >> 4, c = l & 15;

  const uint16_t* Qp = qws + (size_t)bh * NS * NDH;
  const uint16_t* Kp = kws + (size_t)bh * NS * NDH;
  const uint16_t* Vp = vtws + (size_t)bh * NDH * NS;

  // hoist Q fragments (rows q0+w*32 .. +31)
  bf16x8 qf[2][4];
#pragma unroll
  for (int m = 0; m < 2; ++m)
#pragma unroll
    for (int kk = 0; kk < 4; ++kk)
      qf[m][kk] = *(const bf16x8*)&Qp[(size_t)(q0 + w * 32 + m * 16 + c) * NDH + kk * 32 + g * 8];

  f32x4 acc_o[2][8];
  float mreg[2][4], lreg[2][4];
#pragma unroll
  for (int m = 0; m < 2; ++m) {
#pragma unroll
    for (int n = 0; n < 8; ++n) acc_o[m][n] = (f32x4){0.f, 0.f, 0.f, 0.f};
#pragma unroll
    for (int j = 0; j < 4; ++j) { mreg[m][j] = -1e30f; lreg[m][j] = 0.f; }
  }

  const float scale = 0.08838834764831845f;  // 1/sqrt(128)
  int nkt = q0 / 64 + 2;
  for (int kt = 0; kt < nkt; ++kt) {
    // stage K tile [64][128] (16 chunks/row) and V^T tile [128][64] (8 chunks/row)
#pragma unroll
    for (int cc = 0; cc < 4; ++cc) {
      int flat = cc * 256 + t;
      int row = flat >> 4, sub = flat & 15;
      int scol = ((sub ^ (row & 7)) << 3);
      gload_lds16(&Kp[(size_t)(kt * 64 + row) * NDH + scol], (char*)Ksm + flat * 16);
    }
#pragma unroll
    for (int cc = 0; cc < 4; ++cc) {
      int flat = cc * 256 + t;
      int row = flat >> 3, sub = flat & 7;
      int scol = ((sub ^ (row & 7)) << 3);
      gload_lds16(&Vp[(size_t)row * NS + kt * 64 + scol], (char*)Vsm + flat * 16);
    }
    __syncthreads();

    // S = Q K^T  (contract over d: 4 k-steps of 32)
    f32x4 sacc[2][4];
#pragma unroll
    for (int m = 0; m < 2; ++m)
#pragma unroll
      for (int nf = 0; nf < 4; ++nf) sacc[m][nf] = (f32x4){0.f, 0.f, 0.f, 0.f};
#pragma unroll
    for (int kk = 0; kk < 4; ++kk) {
#pragma unroll
      for (int nf = 0; nf < 4; ++nf) {
        int row = nf * 16 + c;
        int kb = ((kk * 32 + g * 8) * 2) ^ ((row & 7) << 4);
        bf16x8 bfr = *(const bf16x8*)((const char*)Ksm + row * 256 + kb);
        sacc[0][nf] = MFMA16(qf[0][kk], bfr, sacc[0][nf]);
        sacc[1][nf] = MFMA16(qf[1][kk], bfr, sacc[1][nf]);
      }
    }

    // scale + causal mask + online softmax (rows: wave-parallel over 16-lane groups)
#pragma unroll
    for (int m = 0; m < 2; ++m) {
#pragma unroll
      for (int j = 0; j < 4; ++j) {
        int r = q0 + w * 32 + m * 16 + g * 4 + j;   // global q row (s index)
#pragma unroll
        for (int nf = 0; nf < 4; ++nf) {
          float sv = sacc[m][nf][j] * scale;
          int col = kt * 64 + nf * 16 + c;
          if (col > r) sv = -1e30f;
          sacc[m][nf][j] = sv;
        }
        float mx = fmaxf(fmaxf(sacc[m][0][j], sacc[m][1][j]),
                         fmaxf(sacc[m][2][j], sacc[m][3][j]));
        mx = fmaxf(mx, __shfl_xor(mx, 1));
        mx = fmaxf(mx, __shfl_xor(mx, 2));
        mx = fmaxf(mx, __shfl_xor(mx, 4));
        mx = fmaxf(mx, __shfl_xor(mx, 8));
        float mold = mreg[m][j];
        float mnew = fmaxf(mold, mx);
        float alpha = __expf(mold - mnew);
        float rs = 0.f;
#pragma unroll
        for (int nf = 0; nf < 4; ++nf) {
          float p = __expf(sacc[m][nf][j] - mnew);
          sacc[m][nf][j] = p;
          rs += p;
        }
        rs += __shfl_xor(rs, 1);
        rs += __shfl_xor(rs, 2);
        rs += __shfl_xor(rs, 4);
        rs += __shfl_xor(rs, 8);
        lreg[m][j] = lreg[m][j] * alpha + rs;
        mreg[m][j] = mnew;
#pragma unroll
        for (int nf = 0; nf < 8; ++nf) acc_o[m][nf][j] *= alpha;
      }
    }

    // P -> LDS (bf16, swizzled), per-wave buffer
#pragma unroll
    for (int m = 0; m < 2; ++m)
#pragma unroll
      for (int nf = 0; nf < 4; ++nf)
#pragma unroll
        for (int j = 0; j < 4; ++j) {
          int row = m * 16 + g * 4 + j;
          int colb = (nf * 16 + c) * 2;
          *(uint16_t*)((char*)Psm[w] + row * 128 + (colb ^ ((row & 7) << 4))) =
              f2bf(sacc[m][nf][j]);
        }

    // O += P V   (contract over kv: 2 k-steps of 32)
#pragma unroll
    for (int kk2 = 0; kk2 < 2; ++kk2) {
      bf16x8 pf[2];
#pragma unroll
      for (int m = 0; m < 2; ++m) {
        int row = m * 16 + c;
        int kb = ((kk2 * 32 + g * 8) * 2) ^ ((row & 7) << 4);
        pf[m] = *(const bf16x8*)((const char*)Psm[w] + row * 128 + kb);
      }
#pragma unroll
      for (int nf = 0; nf < 8; ++nf) {
        int row = nf * 16 + c;
        int kb = ((kk2 * 32 + g * 8) * 2) ^ ((row & 7) << 4);
        bf16x8 vf = *(const bf16x8*)((const char*)Vsm + row * 128 + kb);
        acc_o[0][nf] = MFMA16(pf[0], vf, acc_o[0][nf]);
        acc_o[1][nf] = MFMA16(pf[1], vf, acc_o[1][nf]);
      }
    }
    __syncthreads();
  }

  // normalize + store fp32 out[b][s][h*128+d]
  int bb = bh >> 4, h = bh & 15;
#pragma unroll
  for (int m = 0; m < 2; ++m)
#pragma unroll
    for (int j = 0; j < 4; ++j) {
      int s = q0 + w * 32 + m * 16 + g * 4 + j;
      float inv = 1.0f / lreg[m][j];
      float* op = out + ((size_t)(bb * NS + s)) * NFE + h * NDH;
#pragma unroll
      for (int nf = 0; nf < 8; ++nf) op[nf * 16 + c] = acc_o[m][nf][j] * inv;
    }
}

extern "C" void kernel_launch(void* const* d_in, const int* in_sizes, int n_in,
                              void* d_out, int out_size, void* d_ws, size_t ws_size,
                              hipStream_t stream) {
  const float* in_q = (const float*)d_in[0];
  const float* Wq = (const float*)d_in[1];
  const float* bq = (const float*)d_in[2];
  const float* Wk = (const float*)d_in[3];
  const float* bk = (const float*)d_in[4];
  const float* Wv = (const float*)d_in[5];
  const float* bv = (const float*)d_in[6];
  // d_in[7] = mask (tril causal, hard-coded), d_in[8] = offset
  const int* offp = (const int*)d_in[8];
  float* out = (float*)d_out;

  char* ws = (char*)d_ws;
  const size_t SZ_AQ = (size_t)4096 * 2048 * 2;        // 16 MB
  const size_t SZ_WT = (size_t)3 * 2048 * 2048 * 2;    // 24 MB
  const size_t SZ_TAB = (size_t)2048 * 64 * 4;         // 512 KB
  const size_t SZ_QKV = (size_t)32 * 2048 * 128 * 2;   // 16 MB each
  uint16_t* Aq = (uint16_t*)(ws);
  uint16_t* Wt = (uint16_t*)(ws + SZ_AQ);
  float* cosT = (float*)(ws + SZ_AQ + SZ_WT);
  float* sinT = (float*)(ws + SZ_AQ + SZ_WT + SZ_TAB);
  uint16_t* qws = (uint16_t*)(ws + SZ_AQ + SZ_WT + 2 * SZ_TAB);
  uint16_t* kws = (uint16_t*)(ws + SZ_AQ + SZ_WT + 2 * SZ_TAB + SZ_QKV);
  uint16_t* vws = (uint16_t*)(ws + SZ_AQ + SZ_WT + 2 * SZ_TAB + 2 * SZ_QKV);
  uint16_t* vtws = (uint16_t*)(ws + SZ_AQ + SZ_WT + 2 * SZ_TAB + 3 * SZ_QKV);

  k_convert<<<8192, 256, 0, stream>>>(in_q, Aq);
  k_wt<<<dim3(32, 32, 3), 256, 0, stream>>>(Wq, Wk, Wv, Wt);
  k_rope_tab<<<512, 256, 0, stream>>>(cosT, sinT, offp);
  k_gemm_qkv<<<dim3(32, 48), 256, 0, stream>>>(Aq, Wt, bq, bk, bv, cosT, sinT, qws, kws, vws);
  k_vt<<<dim3(32, 2, 32), 256, 0, stream>>>(vws, vtws);
  k_attn<<<dim3(32, 16), 256, 0, stream>>>(qws, kws, vtws, out);
}

// Round 2
// 233.629 us; speedup vs baseline: 1.0386x; 1.0386x over previous
//
#include <hip/hip_runtime.h>
#include <hip/hip_bf16.h>
#include <stdint.h>

// Problem: B=2, S=2048, F=2048, H=16, DH=128, causal, ROPE_BASE=1e4, fp32 I/O.
#define NB 2
#define NS 2048
#define NFE 2048
#define NH 16
#define NDH 128

// softmax scale folded into q (log2 domain): 1/sqrt(128) * log2(e)
#define QSCALE (0.08838834764831845f * 1.4426950408889634f)

typedef __attribute__((ext_vector_type(4))) float f32x4;
typedef __attribute__((ext_vector_type(8))) __bf16 bf16x8;

__device__ __forceinline__ uint16_t f2bf(float f) {
  uint32_t u = __builtin_bit_cast(uint32_t, f);
  return (uint16_t)((u + 0x7fffu + ((u >> 16) & 1u)) >> 16);
}

__device__ __forceinline__ void gload_lds16(const void* g, void* l) {
  __builtin_amdgcn_global_load_lds((const __attribute__((address_space(1))) void*)g,
                                   (__attribute__((address_space(3))) void*)l,
                                   16, 0, 0);
}

#define MFMA16(a, b, c) __builtin_amdgcn_mfma_f32_16x16x32_bf16(a, b, c, 0, 0, 0)

// ---------------- kernel 0a: fp32 -> bf16 convert (in_q) ----------------
__global__ void k_convert(const float* __restrict__ x, uint16_t* __restrict__ y) {
  int i = (blockIdx.x * 256 + threadIdx.x) * 4;
  float4 v = *(const float4*)(x + i);
  ushort4 o;
  o.x = f2bf(v.x); o.y = f2bf(v.y); o.z = f2bf(v.z); o.w = f2bf(v.w);
  *(ushort4*)(y + i) = o;
}

// ---------------- kernel 0b: W transpose+convert: [K][N] f32 -> [N][K] bf16 ---
__global__ void k_wt(const float* __restrict__ Wq, const float* __restrict__ Wk,
                     const float* __restrict__ Wv, uint16_t* __restrict__ Wt) {
  int which = blockIdx.z;
  const float* Wsrc = (which == 0) ? Wq : ((which == 1) ? Wk : Wv);
  int k0 = blockIdx.x * 64, n0 = blockIdx.y * 64;
  __shared__ uint16_t tile[64][65];
  int t = threadIdx.x;
#pragma unroll
  for (int it = 0; it < 4; ++it) {
    int vec = t + it * 256;        // 0..1023
    int r = vec >> 4, c4 = vec & 15;
    float4 v = *(const float4*)&Wsrc[(size_t)(k0 + r) * NFE + n0 + c4 * 4];
    tile[r][c4 * 4 + 0] = f2bf(v.x);
    tile[r][c4 * 4 + 1] = f2bf(v.y);
    tile[r][c4 * 4 + 2] = f2bf(v.z);
    tile[r][c4 * 4 + 3] = f2bf(v.w);
  }
  __syncthreads();
#pragma unroll
  for (int it = 0; it < 4; ++it) {
    int vec = t + it * 256;
    int r = vec >> 4, c4 = vec & 15;   // r = n row, c4*4 = k offset
    ushort4 o;
    o.x = tile[c4 * 4 + 0][r];
    o.y = tile[c4 * 4 + 1][r];
    o.z = tile[c4 * 4 + 2][r];
    o.w = tile[c4 * 4 + 3][r];
    *(ushort4*)&Wt[(size_t)which * NFE * NFE + (size_t)(n0 + r) * NFE + k0 + c4 * 4] = o;
  }
}

// ---------------- kernel 0c: RoPE cos/sin tables [S][64] fp32 ----------------
__global__ void k_rope_tab(float* __restrict__ cosT, float* __restrict__ sinT,
                           const int* __restrict__ offp) {
  int tid = blockIdx.x * 256 + threadIdx.x;   // 0..131071
  int s = tid >> 6, i = tid & 63;
  float off = (float)offp[0];
  float inv = expf(-((float)i / 64.0f) * logf(10000.0f));
  float ang = ((float)s + off) * inv;
  cosT[tid] = cosf(ang);
  sinT[tid] = sinf(ang);
}

// ---------------- kernel 1: QKV GEMM + bias + RoPE -> bf16 q/k/v ----------------
// A: in_q bf16 [4096][2048]; Wt: [3][2048(n)][2048(k)] bf16.
// tile 128(M) x 128(N), BK=64, 4 waves each 32 rows x 128 cols.
// N-tile == one head of one of {q,k,v}; RoPE pairs (d, d+64) are acc[m][nf] / acc[m][nf+4].
// q additionally scaled by QSCALE (softmax scale, log2 domain).
__global__ __launch_bounds__(256, 2) void k_gemm_qkv(
    const uint16_t* __restrict__ A, const uint16_t* __restrict__ Wt,
    const float* __restrict__ bq, const float* __restrict__ bk, const float* __restrict__ bv,
    const float* __restrict__ cosT, const float* __restrict__ sinT,
    uint16_t* __restrict__ qws, uint16_t* __restrict__ kws, uint16_t* __restrict__ vws) {
  __shared__ alignas(16) uint16_t Asm[128 * 64];
  __shared__ alignas(16) uint16_t Bsm[128 * 64];
  int mt = blockIdx.x;                 // 0..31
  int nt = blockIdx.y;                 // 0..47
  int which = nt >> 4, h = nt & 15;
  const uint16_t* Bsrc = Wt + (size_t)which * NFE * NFE + (size_t)h * NDH * NFE;
  const uint16_t* Arow = A + (size_t)mt * 128 * NFE;
  int t = threadIdx.x, w = t >> 6, l = t & 63;
  int g = l >> 4, c = l & 15;

  f32x4 acc[2][8];
#pragma unroll
  for (int m = 0; m < 2; ++m)
#pragma unroll
    for (int n = 0; n < 8; ++n) acc[m][n] = (f32x4){0.f, 0.f, 0.f, 0.f};

  for (int kt = 0; kt < NFE / 64; ++kt) {
    int k0 = kt * 64;
#pragma unroll
    for (int cc = 0; cc < 4; ++cc) {
      int flat = cc * 256 + t;         // row = flat>>3 (128B rows), sub = flat&7
      int row = flat >> 3, sub = flat & 7;
      int scol = ((sub ^ (row & 7)) << 3) + k0;
      gload_lds16(&Arow[(size_t)row * NFE + scol], (char*)Asm + flat * 16);
    }
#pragma unroll
    for (int cc = 0; cc < 4; ++cc) {
      int flat = cc * 256 + t;
      int row = flat >> 3, sub = flat & 7;
      int scol = ((sub ^ (row & 7)) << 3) + k0;
      gload_lds16(&Bsrc[(size_t)row * NFE + scol], (char*)Bsm + flat * 16);
    }
    __syncthreads();
#pragma unroll
    for (int ks = 0; ks < 2; ++ks) {
      bf16x8 af[2];
#pragma unroll
      for (int m = 0; m < 2; ++m) {
        int row = w * 32 + m * 16 + c;
        int kb = ((ks * 32 + g * 8) * 2) ^ ((row & 7) << 4);
        af[m] = *(const bf16x8*)((const char*)Asm + row * 128 + kb);
      }
#pragma unroll
      for (int nf = 0; nf < 8; ++nf) {
        int row = nf * 16 + c;
        int kb = ((ks * 32 + g * 8) * 2) ^ ((row & 7) << 4);
        bf16x8 bfr = *(const bf16x8*)((const char*)Bsm + row * 128 + kb);
        acc[0][nf] = MFMA16(af[0], bfr, acc[0][nf]);
        acc[1][nf] = MFMA16(af[1], bfr, acc[1][nf]);
      }
    }
    __syncthreads();
  }

  // epilogue: bias (+ RoPE for q,k; + QSCALE for q), write bf16 to [bh][s][d]
  const float* bias = (which == 0) ? bq : ((which == 1) ? bk : bv);
  uint16_t* outp = (which == 0) ? qws : ((which == 1) ? kws : vws);
  float scl = (which == 0) ? QSCALE : 1.0f;
  int mbase = mt * 128 + w * 32;
  if (which < 2) {
#pragma unroll
    for (int m = 0; m < 2; ++m)
#pragma unroll
      for (int nf = 0; nf < 4; ++nf) {
        int i = nf * 16 + c;   // rotary index 0..63
        float b1 = bias[h * NDH + i], b2 = bias[h * NDH + 64 + i];
#pragma unroll
        for (int j = 0; j < 4; ++j) {
          int r = mbase + m * 16 + g * 4 + j;   // global M row
          int bb = r >> 11, s = r & (NS - 1);
          float cs = cosT[(s << 6) + i], sn = sinT[(s << 6) + i];
          float x1 = acc[m][nf][j] + b1;
          float x2 = acc[m][nf + 4][j] + b2;
          uint16_t* op = outp + ((size_t)(bb * NH + h) * NS + s) * NDH;
          op[i] = f2bf((x1 * cs - x2 * sn) * scl);
          op[64 + i] = f2bf((x1 * sn + x2 * cs) * scl);
        }
      }
  } else {
#pragma unroll
    for (int m = 0; m < 2; ++m)
#pragma unroll
      for (int nf = 0; nf < 8; ++nf) {
        int d = nf * 16 + c;
        float bv_ = bias[h * NDH + d];
#pragma unroll
        for (int j = 0; j < 4; ++j) {
          int r = mbase + m * 16 + g * 4 + j;
          int bb = r >> 11, s = r & (NS - 1);
          outp[((size_t)(bb * NH + h) * NS + s) * NDH + d] = f2bf(acc[m][nf][j] + bv_);
        }
      }
  }
}

// ---------------- kernel 1.5: V transpose [bh][s][d] -> [bh][d][s] ----------------
__global__ void k_vt(const uint16_t* __restrict__ v, uint16_t* __restrict__ vt) {
  int bh = blockIdx.z;
  int s0 = blockIdx.x * 64, d0 = blockIdx.y * 64;
  __shared__ uint16_t tile[64][65];
  int t = threadIdx.x;
#pragma unroll
  for (int it = 0; it < 4; ++it) {
    int vec = t + it * 256;
    int r = vec >> 4, c4 = vec & 15;     // r = s row, c4*4 = d offset
    ushort4 x = *(const ushort4*)&v[((size_t)bh * NS + s0 + r) * NDH + d0 + c4 * 4];
    tile[r][c4 * 4 + 0] = x.x;
    tile[r][c4 * 4 + 1] = x.y;
    tile[r][c4 * 4 + 2] = x.z;
    tile[r][c4 * 4 + 3] = x.w;
  }
  __syncthreads();
#pragma unroll
  for (int it = 0; it < 4; ++it) {
    int vec = t + it * 256;
    int r = vec >> 4, c4 = vec & 15;     // r = d row, c4*4 = s offset
    ushort4 o;
    o.x = tile[c4 * 4 + 0][r];
    o.y = tile[c4 * 4 + 1][r];
    o.z = tile[c4 * 4 + 2][r];
    o.w = tile[c4 * 4 + 3][r];
    *(ushort4*)&vt[((size_t)bh * NDH + d0 + r) * NS + s0 + c4 * 4] = o;
  }
}

// ---------------- kernel 2: causal flash attention (paired q-tiles) ----------------
// q (pre-scaled by QSCALE):[32][2048][128], k:[32][2048][128], vT:[32][128][2048] bf16.
// Block: 256 thr / 4 waves; each block handles q-tiles y64 and 31-y64 (64 rows each)
// -> constant 33 k-tile-units per block (causal balance). Wave owns 16 q-rows.
// Softmax in log2 domain (scale folded into q), defer-max THR=8 (log2).
__global__ __launch_bounds__(256, 2) void k_attn(
    const uint16_t* __restrict__ qws, const uint16_t* __restrict__ kws,
    const uint16_t* __restrict__ vtws, float* __restrict__ out) {
  __shared__ alignas(16) uint16_t Ksm[64 * 128];    // [kv][d]  rows 256B, swizzled
  __shared__ alignas(16) uint16_t Vsm[128 * 64];    // [d][kv]  rows 128B, swizzled
  __shared__ alignas(16) uint16_t Psm[4][16 * 64];  // per-wave [q][kv], swizzled

  int bh = blockIdx.x;                 // 0..31 : b = bh>>4, h = bh&15
  int t = threadIdx.x, w = t >> 6, l = t & 63;
  int g = l >> 4, c = l & 15;
  int bb = bh >> 4, h = bh & 15;

  const uint16_t* Qp = qws + (size_t)bh * NS * NDH;
  const uint16_t* Kp = kws + (size_t)bh * NS * NDH;
  const uint16_t* Vp = vtws + (size_t)bh * NDH * NS;

  for (int pass = 0; pass < 2; ++pass) {
    int y64 = pass ? (31 - blockIdx.y) : blockIdx.y;
    int q0 = y64 * 64;

    // hoist Q fragments for this wave's 16 rows
    bf16x8 qf[4];
#pragma unroll
    for (int kk = 0; kk < 4; ++kk)
      qf[kk] = *(const bf16x8*)&Qp[(size_t)(q0 + w * 16 + c) * NDH + kk * 32 + g * 8];

    f32x4 acc_o[8];
    float mreg[4], lreg[4];
#pragma unroll
    for (int n = 0; n < 8; ++n) acc_o[n] = (f32x4){0.f, 0.f, 0.f, 0.f};
#pragma unroll
    for (int j = 0; j < 4; ++j) { mreg[j] = -1e30f; lreg[j] = 0.f; }

    int nkt = y64 + 1;
    for (int kt = 0; kt < nkt; ++kt) {
      // stage K tile [64][128] and V^T tile [128][64]
#pragma unroll
      for (int cc = 0; cc < 4; ++cc) {
        int flat = cc * 256 + t;
        int row = flat >> 4, sub = flat & 15;
        int scol = ((sub ^ (row & 7)) << 3);
        gload_lds16(&Kp[(size_t)(kt * 64 + row) * NDH + scol], (char*)Ksm + flat * 16);
      }
#pragma unroll
      for (int cc = 0; cc < 4; ++cc) {
        int flat = cc * 256 + t;
        int row = flat >> 3, sub = flat & 7;
        int scol = ((sub ^ (row & 7)) << 3);
        gload_lds16(&Vp[(size_t)row * NS + kt * 64 + scol], (char*)Vsm + flat * 16);
      }
      __syncthreads();

      // S = Q K^T (log2-scaled since q carries QSCALE)
      f32x4 sacc[4];
#pragma unroll
      for (int nf = 0; nf < 4; ++nf) sacc[nf] = (f32x4){0.f, 0.f, 0.f, 0.f};
#pragma unroll
      for (int kk = 0; kk < 4; ++kk) {
#pragma unroll
        for (int nf = 0; nf < 4; ++nf) {
          int row = nf * 16 + c;
          int kb = ((kk * 32 + g * 8) * 2) ^ ((row & 7) << 4);
          bf16x8 bfr = *(const bf16x8*)((const char*)Ksm + row * 256 + kb);
          sacc[nf] = MFMA16(qf[kk], bfr, sacc[nf]);
        }
      }

      bool diag = (kt == y64);
#pragma unroll
      for (int j = 0; j < 4; ++j) {
        int r = q0 + w * 16 + g * 4 + j;   // global q row
        if (diag) {
#pragma unroll
          for (int nf = 0; nf < 4; ++nf) {
            int col = kt * 64 + nf * 16 + c;
            if (col > r) sacc[nf][j] = -1e30f;
          }
        }
        float mx = fmaxf(fmaxf(sacc[0][j], sacc[1][j]),
                         fmaxf(sacc[2][j], sacc[3][j]));
        mx = fmaxf(mx, __shfl_xor(mx, 1));
        mx = fmaxf(mx, __shfl_xor(mx, 2));
        mx = fmaxf(mx, __shfl_xor(mx, 4));
        mx = fmaxf(mx, __shfl_xor(mx, 8));
        float mold = mreg[j];
        float mnew = mold;
        if (!__all(mx <= mold + 8.0f)) {   // defer-max: wave-uniform rescale skip
          mnew = fmaxf(mold, mx);
          float alpha = exp2f(mold - mnew);
          mreg[j] = mnew;
          lreg[j] *= alpha;
#pragma unroll
          for (int nf = 0; nf < 8; ++nf) acc_o[nf][j] *= alpha;
        }
        float rs = 0.f;
#pragma unroll
        for (int nf = 0; nf < 4; ++nf) {
          float p = exp2f(sacc[nf][j] - mnew);
          sacc[nf][j] = p;
          rs += p;
        }
        rs += __shfl_xor(rs, 1);
        rs += __shfl_xor(rs, 2);
        rs += __shfl_xor(rs, 4);
        rs += __shfl_xor(rs, 8);
        lreg[j] += rs;
        // P -> LDS (bf16, swizzled), per-wave buffer
#pragma unroll
        for (int nf = 0; nf < 4; ++nf) {
          int row = g * 4 + j;
          int colb = (nf * 16 + c) * 2;
          *(uint16_t*)((char*)Psm[w] + row * 128 + (colb ^ ((row & 7) << 4))) =
              f2bf(sacc[nf][j]);
        }
      }

      // O += P V   (contract over kv: 2 k-steps of 32)
#pragma unroll
      for (int kk2 = 0; kk2 < 2; ++kk2) {
        int prow = c;
        int pkb = ((kk2 * 32 + g * 8) * 2) ^ ((prow & 7) << 4);
        bf16x8 pf = *(const bf16x8*)((const char*)Psm[w] + prow * 128 + pkb);
#pragma unroll
        for (int nf = 0; nf < 8; ++nf) {
          int row = nf * 16 + c;
          int kb = ((kk2 * 32 + g * 8) * 2) ^ ((row & 7) << 4);
          bf16x8 vf = *(const bf16x8*)((const char*)Vsm + row * 128 + kb);
          acc_o[nf] = MFMA16(pf, vf, acc_o[nf]);
        }
      }
      __syncthreads();
    }

    // normalize + store fp32 out[b][s][h*128+d]
#pragma unroll
    for (int j = 0; j < 4; ++j) {
      int s = q0 + w * 16 + g * 4 + j;
      float inv = 1.0f / lreg[j];
      float* op = out + ((size_t)(bb * NS + s)) * NFE + h * NDH;
#pragma unroll
      for (int nf = 0; nf < 8; ++nf) op[nf * 16 + c] = acc_o[nf][j] * inv;
    }
  }
}

extern "C" void kernel_launch(void* const* d_in, const int* in_sizes, int n_in,
                              void* d_out, int out_size, void* d_ws, size_t ws_size,
                              hipStream_t stream) {
  const float* in_q = (const float*)d_in[0];
  const float* Wq = (const float*)d_in[1];
  const float* bq = (const float*)d_in[2];
  const float* Wk = (const float*)d_in[3];
  const float* bk = (const float*)d_in[4];
  const float* Wv = (const float*)d_in[5];
  const float* bv = (const float*)d_in[6];
  // d_in[7] = mask (tril causal, hard-coded), d_in[8] = offset
  const int* offp = (const int*)d_in[8];
  float* out = (float*)d_out;

  char* ws = (char*)d_ws;
  const size_t SZ_AQ = (size_t)4096 * 2048 * 2;        // 16 MB
  const size_t SZ_WT = (size_t)3 * 2048 * 2048 * 2;    // 24 MB
  const size_t SZ_TAB = (size_t)2048 * 64 * 4;         // 512 KB
  const size_t SZ_QKV = (size_t)32 * 2048 * 128 * 2;   // 16 MB each
  uint16_t* Aq = (uint16_t*)(ws);
  uint16_t* Wt = (uint16_t*)(ws + SZ_AQ);
  float* cosT = (float*)(ws + SZ_AQ + SZ_WT);
  float* sinT = (float*)(ws + SZ_AQ + SZ_WT + SZ_TAB);
  uint16_t* qws = (uint16_t*)(ws + SZ_AQ + SZ_WT + 2 * SZ_TAB);
  uint16_t* kws = (uint16_t*)(ws + SZ_AQ + SZ_WT + 2 * SZ_TAB + SZ_QKV);
  uint16_t* vws = (uint16_t*)(ws + SZ_AQ + SZ_WT + 2 * SZ_TAB + 2 * SZ_QKV);
  uint16_t* vtws = (uint16_t*)(ws + SZ_AQ + SZ_WT + 2 * SZ_TAB + 3 * SZ_QKV);

  k_convert<<<8192, 256, 0, stream>>>(in_q, Aq);
  k_wt<<<dim3(32, 32, 3), 256, 0, stream>>>(Wq, Wk, Wv, Wt);
  k_rope_tab<<<512, 256, 0, stream>>>(cosT, sinT, offp);
  k_gemm_qkv<<<dim3(32, 48), 256, 0, stream>>>(Aq, Wt, bq, bk, bv, cosT, sinT, qws, kws, vws);
  k_vt<<<dim3(32, 2, 32), 256, 0, stream>>>(vws, vtws);
  k_attn<<<dim3(32, 16), 256, 0, stream>>>(qws, kws, vtws, out);
}

// Round 3
// 210.241 us; speedup vs baseline: 1.1541x; 1.1112x over previous
//
#include <hip/hip_runtime.h>
#include <hip/hip_bf16.h>
#include <stdint.h>

// Problem: B=2, S=2048, F=2048, H=16, DH=128, causal, ROPE_BASE=1e4, fp32 I/O.
#define NB 2
#define NS 2048
#define NFE 2048
#define NH 16
#define NDH 128

// softmax scale folded into q (log2 domain): 1/sqrt(128) * log2(e)
#define QSCALE (0.08838834764831845f * 1.4426950408889634f)

typedef __attribute__((ext_vector_type(4))) float f32x4;
typedef __attribute__((ext_vector_type(8))) __bf16 bf16x8;

__device__ __forceinline__ uint16_t f2bf(float f) {
  uint32_t u = __builtin_bit_cast(uint32_t, f);
  return (uint16_t)((u + 0x7fffu + ((u >> 16) & 1u)) >> 16);
}

__device__ __forceinline__ void gload_lds16(const void* g, void* l) {
  __builtin_amdgcn_global_load_lds((const __attribute__((address_space(1))) void*)g,
                                   (__attribute__((address_space(3))) void*)l,
                                   16, 0, 0);
}

#define MFMA16(a, b, c) __builtin_amdgcn_mfma_f32_16x16x32_bf16(a, b, c, 0, 0, 0)

// ---------------- kernel 0a: fp32 -> bf16 convert (in_q) ----------------
__global__ void k_convert(const float* __restrict__ x, uint16_t* __restrict__ y) {
  int i = (blockIdx.x * 256 + threadIdx.x) * 4;
  float4 v = *(const float4*)(x + i);
  ushort4 o;
  o.x = f2bf(v.x); o.y = f2bf(v.y); o.z = f2bf(v.z); o.w = f2bf(v.w);
  *(ushort4*)(y + i) = o;
}

// ---------------- kernel 0b: W transpose+convert: [K][N] f32 -> [N][K] bf16 ---
__global__ void k_wt(const float* __restrict__ Wq, const float* __restrict__ Wk,
                     const float* __restrict__ Wv, uint16_t* __restrict__ Wt) {
  int which = blockIdx.z;
  const float* Wsrc = (which == 0) ? Wq : ((which == 1) ? Wk : Wv);
  int k0 = blockIdx.x * 64, n0 = blockIdx.y * 64;
  __shared__ uint16_t tile[64][65];
  int t = threadIdx.x;
#pragma unroll
  for (int it = 0; it < 4; ++it) {
    int vec = t + it * 256;        // 0..1023
    int r = vec >> 4, c4 = vec & 15;
    float4 v = *(const float4*)&Wsrc[(size_t)(k0 + r) * NFE + n0 + c4 * 4];
    tile[r][c4 * 4 + 0] = f2bf(v.x);
    tile[r][c4 * 4 + 1] = f2bf(v.y);
    tile[r][c4 * 4 + 2] = f2bf(v.z);
    tile[r][c4 * 4 + 3] = f2bf(v.w);
  }
  __syncthreads();
#pragma unroll
  for (int it = 0; it < 4; ++it) {
    int vec = t + it * 256;
    int r = vec >> 4, c4 = vec & 15;   // r = n row, c4*4 = k offset
    ushort4 o;
    o.x = tile[c4 * 4 + 0][r];
    o.y = tile[c4 * 4 + 1][r];
    o.z = tile[c4 * 4 + 2][r];
    o.w = tile[c4 * 4 + 3][r];
    *(ushort4*)&Wt[(size_t)which * NFE * NFE + (size_t)(n0 + r) * NFE + k0 + c4 * 4] = o;
  }
}

// ---------------- kernel 0c: RoPE cos/sin tables [S][64] fp32 ----------------
__global__ void k_rope_tab(float* __restrict__ cosT, float* __restrict__ sinT,
                           const int* __restrict__ offp) {
  int tid = blockIdx.x * 256 + threadIdx.x;   // 0..131071
  int s = tid >> 6, i = tid & 63;
  float off = (float)offp[0];
  float inv = expf(-((float)i / 64.0f) * logf(10000.0f));
  float ang = ((float)s + off) * inv;
  cosT[tid] = cosf(ang);
  sinT[tid] = sinf(ang);
}

// ---------------- kernel 1: QKV GEMM + bias + RoPE -> bf16 q/k/v ----------------
__global__ __launch_bounds__(256, 2) void k_gemm_qkv(
    const uint16_t* __restrict__ A, const uint16_t* __restrict__ Wt,
    const float* __restrict__ bq, const float* __restrict__ bk, const float* __restrict__ bv,
    const float* __restrict__ cosT, const float* __restrict__ sinT,
    uint16_t* __restrict__ qws, uint16_t* __restrict__ kws, uint16_t* __restrict__ vws) {
  __shared__ alignas(16) uint16_t Asm[128 * 64];
  __shared__ alignas(16) uint16_t Bsm[128 * 64];
  int mt = blockIdx.x;                 // 0..31
  int nt = blockIdx.y;                 // 0..47
  int which = nt >> 4, h = nt & 15;
  const uint16_t* Bsrc = Wt + (size_t)which * NFE * NFE + (size_t)h * NDH * NFE;
  const uint16_t* Arow = A + (size_t)mt * 128 * NFE;
  int t = threadIdx.x, w = t >> 6, l = t & 63;
  int g = l >> 4, c = l & 15;

  f32x4 acc[2][8];
#pragma unroll
  for (int m = 0; m < 2; ++m)
#pragma unroll
    for (int n = 0; n < 8; ++n) acc[m][n] = (f32x4){0.f, 0.f, 0.f, 0.f};

  for (int kt = 0; kt < NFE / 64; ++kt) {
    int k0 = kt * 64;
#pragma unroll
    for (int cc = 0; cc < 4; ++cc) {
      int flat = cc * 256 + t;         // row = flat>>3 (128B rows), sub = flat&7
      int row = flat >> 3, sub = flat & 7;
      int scol = ((sub ^ (row & 7)) << 3) + k0;
      gload_lds16(&Arow[(size_t)row * NFE + scol], (char*)Asm + flat * 16);
    }
#pragma unroll
    for (int cc = 0; cc < 4; ++cc) {
      int flat = cc * 256 + t;
      int row = flat >> 3, sub = flat & 7;
      int scol = ((sub ^ (row & 7)) << 3) + k0;
      gload_lds16(&Bsrc[(size_t)row * NFE + scol], (char*)Bsm + flat * 16);
    }
    __syncthreads();
#pragma unroll
    for (int ks = 0; ks < 2; ++ks) {
      bf16x8 af[2];
#pragma unroll
      for (int m = 0; m < 2; ++m) {
        int row = w * 32 + m * 16 + c;
        int kb = ((ks * 32 + g * 8) * 2) ^ ((row & 7) << 4);
        af[m] = *(const bf16x8*)((const char*)Asm + row * 128 + kb);
      }
#pragma unroll
      for (int nf = 0; nf < 8; ++nf) {
        int row = nf * 16 + c;
        int kb = ((ks * 32 + g * 8) * 2) ^ ((row & 7) << 4);
        bf16x8 bfr = *(const bf16x8*)((const char*)Bsm + row * 128 + kb);
        acc[0][nf] = MFMA16(af[0], bfr, acc[0][nf]);
        acc[1][nf] = MFMA16(af[1], bfr, acc[1][nf]);
      }
    }
    __syncthreads();
  }

  // epilogue: bias (+ RoPE for q,k; + QSCALE for q), write bf16 to [bh][s][d]
  const float* bias = (which == 0) ? bq : ((which == 1) ? bk : bv);
  uint16_t* outp = (which == 0) ? qws : ((which == 1) ? kws : vws);
  float scl = (which == 0) ? QSCALE : 1.0f;
  int mbase = mt * 128 + w * 32;
  if (which < 2) {
#pragma unroll
    for (int m = 0; m < 2; ++m)
#pragma unroll
      for (int nf = 0; nf < 4; ++nf) {
        int i = nf * 16 + c;   // rotary index 0..63
        float b1 = bias[h * NDH + i], b2 = bias[h * NDH + 64 + i];
#pragma unroll
        for (int j = 0; j < 4; ++j) {
          int r = mbase + m * 16 + g * 4 + j;   // global M row
          int bb = r >> 11, s = r & (NS - 1);
          float cs = cosT[(s << 6) + i], sn = sinT[(s << 6) + i];
          float x1 = acc[m][nf][j] + b1;
          float x2 = acc[m][nf + 4][j] + b2;
          uint16_t* op = outp + ((size_t)(bb * NH + h) * NS + s) * NDH;
          op[i] = f2bf((x1 * cs - x2 * sn) * scl);
          op[64 + i] = f2bf((x1 * sn + x2 * cs) * scl);
        }
      }
  } else {
#pragma unroll
    for (int m = 0; m < 2; ++m)
#pragma unroll
      for (int nf = 0; nf < 8; ++nf) {
        int d = nf * 16 + c;
        float bv_ = bias[h * NDH + d];
#pragma unroll
        for (int j = 0; j < 4; ++j) {
          int r = mbase + m * 16 + g * 4 + j;
          int bb = r >> 11, s = r & (NS - 1);
          outp[((size_t)(bb * NH + h) * NS + s) * NDH + d] = f2bf(acc[m][nf][j] + bv_);
        }
      }
  }
}

// ---------------- kernel 1.5: V transpose [bh][s][d] -> [bh][d][s] ----------------
__global__ void k_vt(const uint16_t* __restrict__ v, uint16_t* __restrict__ vt) {
  int bh = blockIdx.z;
  int s0 = blockIdx.x * 64, d0 = blockIdx.y * 64;
  __shared__ uint16_t tile[64][65];
  int t = threadIdx.x;
#pragma unroll
  for (int it = 0; it < 4; ++it) {
    int vec = t + it * 256;
    int r = vec >> 4, c4 = vec & 15;     // r = s row, c4*4 = d offset
    ushort4 x = *(const ushort4*)&v[((size_t)bh * NS + s0 + r) * NDH + d0 + c4 * 4];
    tile[r][c4 * 4 + 0] = x.x;
    tile[r][c4 * 4 + 1] = x.y;
    tile[r][c4 * 4 + 2] = x.z;
    tile[r][c4 * 4 + 3] = x.w;
  }
  __syncthreads();
#pragma unroll
  for (int it = 0; it < 4; ++it) {
    int vec = t + it * 256;
    int r = vec >> 4, c4 = vec & 15;     // r = d row, c4*4 = s offset
    ushort4 o;
    o.x = tile[c4 * 4 + 0][r];
    o.y = tile[c4 * 4 + 1][r];
    o.z = tile[c4 * 4 + 2][r];
    o.w = tile[c4 * 4 + 3][r];
    *(ushort4*)&vt[((size_t)bh * NDH + d0 + r) * NS + s0 + c4 * 4] = o;
  }
}

// ---------------- kernel 2: causal flash attention (paired q-tiles) ----------------
// Swapped QK^T: S^T = mfma(K, Q) => each lane owns q-row (lane&15), kv in regs.
// Softmax register-local: 2 shfl_xor reduces, per-lane m/l scalars.
// q pre-scaled by QSCALE (log2 domain); defer-max THR=8.
__global__ __launch_bounds__(256, 4) void k_attn(
    const uint16_t* __restrict__ qws, const uint16_t* __restrict__ kws,
    const uint16_t* __restrict__ vtws, float* __restrict__ out) {
  __shared__ alignas(16) uint16_t Ksm[64 * 128];    // [kv][d]  rows 256B, swizzled
  __shared__ alignas(16) uint16_t Vsm[128 * 64];    // [d][kv]  rows 128B, swizzled
  __shared__ alignas(16) uint16_t Psm[4][16 * 64];  // per-wave [q][kv], swizzled

  int bh = blockIdx.x;                 // 0..31 : b = bh>>4, h = bh&15
  int t = threadIdx.x, w = t >> 6, l = t & 63;
  int g = l >> 4, c = l & 15;
  int bb = bh >> 4, h = bh & 15;

  const uint16_t* Qp = qws + (size_t)bh * NS * NDH;
  const uint16_t* Kp = kws + (size_t)bh * NS * NDH;
  const uint16_t* Vp = vtws + (size_t)bh * NDH * NS;

  for (int pass = 0; pass < 2; ++pass) {
    int y64 = pass ? (31 - blockIdx.y) : blockIdx.y;
    int q0 = y64 * 64;
    int r = q0 + w * 16 + c;           // this lane's q row (col of S^T)

    // hoist Q fragments (B-operand: col=lane&15=q row, k = g*8.. within kk*32)
    bf16x8 qf[4];
#pragma unroll
    for (int kk = 0; kk < 4; ++kk)
      qf[kk] = *(const bf16x8*)&Qp[(size_t)r * NDH + kk * 32 + g * 8];

    f32x4 acc_o[8];
    float mreg = -1e30f, lreg = 0.f;
#pragma unroll
    for (int n = 0; n < 8; ++n) acc_o[n] = (f32x4){0.f, 0.f, 0.f, 0.f};

    int nkt = y64 + 1;
    for (int kt = 0; kt < nkt; ++kt) {
      // stage K tile [64][128] and V^T tile [128][64]
#pragma unroll
      for (int cc = 0; cc < 4; ++cc) {
        int flat = cc * 256 + t;
        int row = flat >> 4, sub = flat & 15;
        int scol = ((sub ^ (row & 7)) << 3);
        gload_lds16(&Kp[(size_t)(kt * 64 + row) * NDH + scol], (char*)Ksm + flat * 16);
      }
#pragma unroll
      for (int cc = 0; cc < 4; ++cc) {
        int flat = cc * 256 + t;
        int row = flat >> 3, sub = flat & 7;
        int scol = ((sub ^ (row & 7)) << 3);
        gload_lds16(&Vp[(size_t)row * NS + kt * 64 + scol], (char*)Vsm + flat * 16);
      }
      __syncthreads();

      // S^T = K Q^T : sacc[nf][j] = S[q=r][kv = kt*64 + nf*16 + g*4 + j]
      f32x4 sacc[4];
#pragma unroll
      for (int nf = 0; nf < 4; ++nf) sacc[nf] = (f32x4){0.f, 0.f, 0.f, 0.f};
#pragma unroll
      for (int kk = 0; kk < 4; ++kk) {
#pragma unroll
        for (int nf = 0; nf < 4; ++nf) {
          int row = nf * 16 + c;
          int kb = ((kk * 32 + g * 8) * 2) ^ ((row & 7) << 4);
          bf16x8 kfr = *(const bf16x8*)((const char*)Ksm + row * 256 + kb);
          sacc[nf] = MFMA16(kfr, qf[kk], sacc[nf]);   // swapped operands
        }
      }

      // causal mask (diagonal tile only)
      if (kt == y64) {
#pragma unroll
        for (int nf = 0; nf < 4; ++nf)
#pragma unroll
          for (int j = 0; j < 4; ++j) {
            int kv = kt * 64 + nf * 16 + g * 4 + j;
            if (kv > r) sacc[nf][j] = -1e30f;
          }
      }

      // register-local row max (this lane's 16 kv values) + 2-shfl combine
      float mx = -1e30f;
#pragma unroll
      for (int nf = 0; nf < 4; ++nf)
        mx = fmaxf(mx, fmaxf(fmaxf(sacc[nf][0], sacc[nf][1]),
                             fmaxf(sacc[nf][2], sacc[nf][3])));
      mx = fmaxf(mx, __shfl_xor(mx, 16));
      mx = fmaxf(mx, __shfl_xor(mx, 32));

      float mnew = mreg;
      if (!__all(mx <= mreg + 8.0f)) {   // defer-max: wave-uniform rescale skip
        mnew = fmaxf(mreg, mx);
        float alpha = exp2f(mreg - mnew);
        mreg = mnew;
        lreg *= alpha;
#pragma unroll
        for (int j = 0; j < 4; ++j) {
          float aj = __shfl(alpha, (l & 48) + g * 4 + j);  // alpha of acc_o's q row
#pragma unroll
          for (int nf = 0; nf < 8; ++nf) acc_o[nf][j] *= aj;
        }
      }

      float rs = 0.f;
#pragma unroll
      for (int nf = 0; nf < 4; ++nf)
#pragma unroll
        for (int j = 0; j < 4; ++j) {
          float p = exp2f(sacc[nf][j] - mnew);
          sacc[nf][j] = p;
          rs += p;
        }
      rs += __shfl_xor(rs, 16);
      rs += __shfl_xor(rs, 32);
      lreg += rs;

      // P -> LDS (packed b32 writes): row = q = c, col = kv
#pragma unroll
      for (int nf = 0; nf < 4; ++nf) {
        uint32_t pk0 = (uint32_t)f2bf(sacc[nf][0]) | ((uint32_t)f2bf(sacc[nf][1]) << 16);
        uint32_t pk1 = (uint32_t)f2bf(sacc[nf][2]) | ((uint32_t)f2bf(sacc[nf][3]) << 16);
        int colb = (nf * 16 + g * 4) * 2;
        char* base = (char*)Psm[w] + c * 128;
        *(uint32_t*)(base + (colb ^ ((c & 7) << 4))) = pk0;
        *(uint32_t*)(base + ((colb + 4) ^ ((c & 7) << 4))) = pk1;
      }

      // O += P V   (contract over kv: 2 k-steps of 32)
#pragma unroll
      for (int kk2 = 0; kk2 < 2; ++kk2) {
        int prow = c;
        int pkb = ((kk2 * 32 + g * 8) * 2) ^ ((prow & 7) << 4);
        bf16x8 pf = *(const bf16x8*)((const char*)Psm[w] + prow * 128 + pkb);
#pragma unroll
        for (int nf = 0; nf < 8; ++nf) {
          int row = nf * 16 + c;
          int kb = ((kk2 * 32 + g * 8) * 2) ^ ((row & 7) << 4);
          bf16x8 vf = *(const bf16x8*)((const char*)Vsm + row * 128 + kb);
          acc_o[nf] = MFMA16(pf, vf, acc_o[nf]);
        }
      }
      __syncthreads();
    }

    // normalize + store fp32 out[b][s][h*128+d]
#pragma unroll
    for (int j = 0; j < 4; ++j) {
      float lj = __shfl(lreg, (l & 48) + g * 4 + j);
      float inv = 1.0f / lj;
      int s = q0 + w * 16 + g * 4 + j;
      float* op = out + ((size_t)(bb * NS + s)) * NFE + h * NDH;
#pragma unroll
      for (int nf = 0; nf < 8; ++nf) op[nf * 16 + c] = acc_o[nf][j] * inv;
    }
  }
}

extern "C" void kernel_launch(void* const* d_in, const int* in_sizes, int n_in,
                              void* d_out, int out_size, void* d_ws, size_t ws_size,
                              hipStream_t stream) {
  const float* in_q = (const float*)d_in[0];
  const float* Wq = (const float*)d_in[1];
  const float* bq = (const float*)d_in[2];
  const float* Wk = (const float*)d_in[3];
  const float* bk = (const float*)d_in[4];
  const float* Wv = (const float*)d_in[5];
  const float* bv = (const float*)d_in[6];
  // d_in[7] = mask (tril causal, hard-coded), d_in[8] = offset
  const int* offp = (const int*)d_in[8];
  float* out = (float*)d_out;

  char* ws = (char*)d_ws;
  const size_t SZ_AQ = (size_t)4096 * 2048 * 2;        // 16 MB
  const size_t SZ_WT = (size_t)3 * 2048 * 2048 * 2;    // 24 MB
  const size_t SZ_TAB = (size_t)2048 * 64 * 4;         // 512 KB
  const size_t SZ_QKV = (size_t)32 * 2048 * 128 * 2;   // 16 MB each
  uint16_t* Aq = (uint16_t*)(ws);
  uint16_t* Wt = (uint16_t*)(ws + SZ_AQ);
  float* cosT = (float*)(ws + SZ_AQ + SZ_WT);
  float* sinT = (float*)(ws + SZ_AQ + SZ_WT + SZ_TAB);
  uint16_t* qws = (uint16_t*)(ws + SZ_AQ + SZ_WT + 2 * SZ_TAB);
  uint16_t* kws = (uint16_t*)(ws + SZ_AQ + SZ_WT + 2 * SZ_TAB + SZ_QKV);
  uint16_t* vws = (uint16_t*)(ws + SZ_AQ + SZ_WT + 2 * SZ_TAB + 2 * SZ_QKV);
  uint16_t* vtws = (uint16_t*)(ws + SZ_AQ + SZ_WT + 2 * SZ_TAB + 3 * SZ_QKV);

  k_convert<<<8192, 256, 0, stream>>>(in_q, Aq);
  k_wt<<<dim3(32, 32, 3), 256, 0, stream>>>(Wq, Wk, Wv, Wt);
  k_rope_tab<<<512, 256, 0, stream>>>(cosT, sinT, offp);
  k_gemm_qkv<<<dim3(32, 48), 256, 0, stream>>>(Aq, Wt, bq, bk, bv, cosT, sinT, qws, kws, vws);
  k_vt<<<dim3(32, 2, 32), 256, 0, stream>>>(vws, vtws);
  k_attn<<<dim3(32, 16), 256, 0, stream>>>(qws, kws, vtws, out);
}